// Round 17
// baseline (59.042 us; speedup 1.0000x reference)
//
#include <hip/hip_runtime.h>
#include <hip/hip_bf16.h>

// Problem constants
#define NB 32      // batch
#define NC 8       // channels
#define NL 512     // length
#define NS 63      // scales
#define NK 1009    // max wavelet kernel length (odd)
#define NPAD 504   // (NK-1)/2
#define ND 512     // d_model
#define NCT 512    // total channels after concat = C*(1+S)
#define NROWS 514  // Apad rows per batch (circular-padded)

typedef __attribute__((ext_vector_type(4))) float f32x4;
typedef __attribute__((ext_vector_type(8))) short short8;

// Workspace layout (bytes)
#define APAD_BYTES (NB * NROWS * NL * 2)   // 16,842,752  bf16 [B][514][512]
#define WBF_BYTES  (3 * ND * NL * 2)       //  1,572,864  bf16 fragment layout
#define KAP_STRIDE (32 * 16 * 64 * 8)      // 262144 elems per kap plane

typedef const __attribute__((address_space(1))) unsigned int* gp1_t;
typedef __attribute__((address_space(3))) unsigned int* lp3_t;
__device__ __forceinline__ void gload_lds16(const void* g, void* l) {
  __builtin_amdgcn_global_load_lds((gp1_t)g, (lp3_t)l, 16, 0, 0);
}

__device__ __forceinline__ unsigned short bf16_bits(float v) {
  return __builtin_bit_cast(unsigned short, __float2bfloat16(v));
}

#define WAITVM(N) asm volatile("s_waitcnt vmcnt(" #N ")" ::: "memory")
#define FENCE() asm volatile("" ::: "memory")
#define BAR() __builtin_amdgcn_s_barrier()
#define PRIO1() __builtin_amdgcn_s_setprio(1)
#define PRIO0() __builtin_amdgcn_s_setprio(0)

// ---------------------------------------------------------------------------
// Kernel 1: prep — WbF in MFMA-fragment layout; bankB[s][k] zero-padded.
// WbF elem index: ((kap*32 + o/16)*16 + l/32)*512 + lane*8 + l%8,
//   lane = (o%16) + 16*((l%32)/8). A wave's B-fragment = 1 KB contiguous.
// ---------------------------------------------------------------------------
__global__ __launch_bounds__(256) void prep_kernel(
    const float* __restrict__ bank, const float* __restrict__ tw,
    __hip_bfloat16* __restrict__ WbF, __hip_bfloat16* __restrict__ bankB) {
  const int idx = blockIdx.x * 256 + threadIdx.x;   // 65536 threads

  {
    int i0 = idx * 4;                  // 4 consecutive i = same o, l..l+3
    const float4* t4 = (const float4*)(tw + (size_t)i0 * 3);
    float4 a = t4[0], bq = t4[1], c4 = t4[2];
    ushort4 w0 = make_ushort4(bf16_bits(a.x), bf16_bits(a.w), bf16_bits(bq.z), bf16_bits(c4.y));
    ushort4 w1 = make_ushort4(bf16_bits(a.y), bf16_bits(bq.x), bf16_bits(bq.w), bf16_bits(c4.z));
    ushort4 w2 = make_ushort4(bf16_bits(a.z), bf16_bits(bq.y), bf16_bits(c4.x), bf16_bits(c4.w));
    int o = i0 >> 9, l = i0 & 511;
    int og = o >> 4, ri = o & 15;
    int ksg = l >> 5, h2 = (l >> 3) & 3, e0 = l & 7;   // e0 in {0,4}
    int base = ((og * 16 + ksg) * 64 + (ri + 16 * h2)) * 8 + e0;
    *(ushort4*)(WbF + 0 * KAP_STRIDE + base) = w0;
    *(ushort4*)(WbF + 1 * KAP_STRIDE + base) = w1;
    *(ushort4*)(WbF + 2 * KAP_STRIDE + base) = w2;
  }
  {
    int s = idx >> 10, k = idx & 1023;
    float v = (s < NS && k < NK) ? bank[s * NK + k] : 0.f;
    bankB[idx] = __float2bfloat16(v);
  }
}

// ---------------------------------------------------------------------------
// Kernel 2: cwt via MFMA (unchanged from R13/R16 — measured best).
// ---------------------------------------------------------------------------
#define CPY8_STRIDE 3152   // 16*197, 197 odd -> quad spread across copies

__global__ __launch_bounds__(512) void cwt_kernel(
    const float* __restrict__ x, const __hip_bfloat16* __restrict__ bankB,
    __hip_bfloat16* __restrict__ Apad) {
  __shared__ __align__(16) char smem[8 * 16384 + 8 * CPY8_STRIDE];  // 156,288 B
  char* bankS = smem;
  char* cpy = smem + 8 * 16384;

  const int tid = threadIdx.x;
  const int bc = blockIdx.x;
  const int b = bc >> 3, c = bc & 7;
  const int w = tid >> 6, l = tid & 63;
  const int hi = l >> 4, li = l & 15;
  const int r8 = l & 7;

  const float* xrow = x + bc * NL;

  if (tid < 512) {
    __hip_bfloat16 v = __float2bfloat16(xrow[tid]);
    Apad[((size_t)(b * NROWS) + 1 + c) * NL + tid] = v;
    if (c == 0) Apad[((size_t)(b * NROWS) + 513) * NL + tid] = v;
  }

  for (int i = 0; i < 13; ++i) {
    int p = tid + i * 512;
    if (p < 6176) {
      int r_ = p / 772;
      int pe = p - r_ * 772;
      int g0 = 2 * pe;
      int i0 = g0 - 8 + r_;
      float xa = (i0 >= NPAD && i0 < NPAD + NL) ? xrow[i0 - NPAD] : 0.f;
      float xb = (i0 + 1 >= NPAD && i0 + 1 < NPAD + NL) ? xrow[i0 + 1 - NPAD] : 0.f;
      float xc = (i0 + 2 >= NPAD && i0 + 2 < NPAD + NL) ? xrow[i0 + 2 - NPAD] : 0.f;
      unsigned u = (unsigned)bf16_bits(xb - xa) | ((unsigned)bf16_bits(xc - xb) << 16);
      *(unsigned*)(cpy + r_ * CPY8_STRIDE + g0 * 2) = u;
    }
  }

#define STAGE(kt)                                                             \
  {                                                                           \
    for (int i = 0; i < 2; ++i) {                                             \
      int ck = tid + i * 512;                                                 \
      int s_ = ck >> 4, rb = ck & 15;                                         \
      int srcc = rb ^ (s_ & 7);                                               \
      gload_lds16(bankB + s_ * 1024 + (kt) * 128 + srcc * 8,                  \
                  bankS + (kt) * 16384 + ck * 16);                            \
    }                                                                         \
  }

#define AVMM(kt, ksl, m)                                                       \
  {                                                                            \
    int srow = (m) * 16 + li;                                                  \
    int chunk = ((ksl) * 4 + hi) ^ (srow & 7);                                 \
    short8 av = *(const short8*)(bankS + (kt) * 16384 + srow * 256 + chunk * 16); \
    _Pragma("unroll") for (int n = 0; n < 4; ++n)                              \
      acc[m][n] = __builtin_amdgcn_mfma_f32_16x16x32_bf16(av, bv[n],           \
                                                          acc[m][n], 0, 0, 0); \
  }

#define CCOMP(kt, M0, M1, M2, M3)                                              \
  {                                                                            \
    _Pragma("unroll") for (int ksl = 0; ksl < 4; ++ksl) {                      \
      short8 bv[4];                                                            \
      _Pragma("unroll") for (int n = 0; n < 4; ++n) {                          \
        int ebyte = 16 + 2 * (tbase + n * 16 + 8 * (li >> 3) +                 \
                              (kt) * 128 + ksl * 32 + 8 * hi);                 \
        bv[n] = *(const short8*)(cpy + r8 * CPY8_STRIDE + ebyte);              \
      }                                                                        \
      if (M0) AVMM(kt, ksl, 0);                                                \
      if (M1) AVMM(kt, ksl, 1);                                                \
      if (M2) AVMM(kt, ksl, 2);                                                \
      if (M3) AVMM(kt, ksl, 3);                                                \
    }                                                                          \
  }

  STAGE(0); STAGE(1); STAGE(2); STAGE(3);
  STAGE(4); STAGE(5); STAGE(6); STAGE(7);

  f32x4 acc[4][4] = {};
  const int tbase = w * 64;

  asm volatile("s_waitcnt vmcnt(14) lgkmcnt(0)" ::: "memory");
  BAR(); FENCE(); CCOMP(0, 0, 0, 1, 1);
  WAITVM(12); BAR(); FENCE(); CCOMP(1, 0, 1, 1, 1);
  WAITVM(10); BAR(); FENCE(); CCOMP(2, 1, 1, 1, 1);
  WAITVM(8);  BAR(); FENCE(); CCOMP(3, 1, 1, 1, 1);
  WAITVM(6);  BAR(); FENCE(); CCOMP(4, 1, 1, 1, 1);
  WAITVM(4);  BAR(); FENCE(); CCOMP(5, 0, 1, 1, 1);
  WAITVM(2);  BAR(); FENCE(); CCOMP(6, 0, 0, 1, 1);
  WAITVM(0);  BAR(); FENCE(); CCOMP(7, 0, 0, 0, 1);

#pragma unroll
  for (int m = 0; m < 4; ++m) {
#pragma unroll
    for (int rg = 0; rg < 4; ++rg) {
      int s = m * 16 + hi * 4 + rg;
      if (s >= NS) continue;
      int ch = 8 + c * NS + s;
      size_t rowbase = ((size_t)(b * NROWS) + 1 + ch) * NL;
#pragma unroll
      for (int n = 0; n < 4; ++n) {
        int t = tbase + n * 16 + li;
        float d = fabsf(acc[m][n][rg]);
        __hip_bfloat16 hv = __float2bfloat16(d);
        bool lastgrp = (w == 7 && n == 3);
        bool skip = lastgrp && (li == 15);
        bool dup = lastgrp && (li == 14);
        if (!skip) Apad[rowbase + t] = hv;
        if (dup) Apad[rowbase + 511] = hv;
        if (ch == NCT - 1) {
          size_t wrapbase = (size_t)(b * NROWS) * NL;
          if (!skip) Apad[wrapbase + t] = hv;
          if (dup) Apad[wrapbase + 511] = hv;
        }
      }
    }
  }
#undef STAGE
#undef AVMM
#undef CCOMP
}

// ---------------------------------------------------------------------------
// Kernel 3: gemm — BM=256, BN=128, BK=64, 8 waves (4Mx2N).
// A: LDS (3-buf rotation, 96 KB, T2 swizzle, gload_lds) — read 2x from LDS.
// B: MFMA-fragment-layout GLOBAL reads into registers (depth-2 prefetch,
//    3 static sets bvA/bvB/bvC) — removes B from LDS entirely. LDS port per
//    tile drops 176 KB -> 96 KB (below MFMA time). bv uses are compiler-
//    vmcnt'd (reg dataflow); manual WAITVM(20) covers A-staging only:
//    in-flight = bv(kt)8 + A(kt+1)4 + bv(kt+1)8 = 20. Hazard skeleton = R16.
// ---------------------------------------------------------------------------
__global__ __launch_bounds__(512) void gemm_kernel(
    const __hip_bfloat16* __restrict__ Ap, const __hip_bfloat16* __restrict__ WbF,
    float* __restrict__ out) {
  __shared__ __hip_bfloat16 sA[3][256 * 64];   // 96 KB

  const int tid = threadIdx.x;                 // 0..511
  const int gid = blockIdx.x;                  // 0..255
  const int idx = gid >> 3;                    // 0..31
  const int mblk = (gid & 7) * 8 + (idx & 7);  // 0..63 (XCD-local A-slab)
  const int nblk = idx >> 3;                   // 0..3
  const int b = mblk >> 1;
  const int p0 = (mblk & 1) * 256;
  const int o0 = nblk * 128;

  const int w = tid >> 6, lane = tid & 63;
  const int wm = w >> 1, wn = w & 1;           // 4M x 2N
  const int row_in = lane & 15, hi = lane >> 4;
  const int og0 = (o0 >> 4) + wn * 4;          // B fragment o-group base

// stage A-chunk pair i0,i1 of tile kt into buffer bu (T2 source swizzle)
#define GS_A(kt, bu, i0, i1)                                                   \
  {                                                                            \
    const int kap_ = (kt) >> 3;                                                \
    const int l0_ = ((kt) & 7) << 6;                                           \
    _Pragma("unroll") for (int i = (i0); i <= (i1); ++i) {                     \
      int ck = tid + i * 512;                                                  \
      int row = ck >> 3, cg = (ck & 7) ^ (row & 7);                            \
      gload_lds16(Ap + ((b * NROWS + p0 + kap_ + row) * NL + l0_ + cg * 8),    \
                  &sA[bu][ck * 8]);                                            \
    }                                                                          \
  }

// load 4 B-fragments (k-slice ks of tile ktn) into register set half
#define BVL(ktn, SET, ks)                                                      \
  {                                                                            \
    const int kap_ = (ktn) >> 3;                                               \
    const int ksg_ = ((ktn) & 7) * 2 + (ks);                                   \
    _Pragma("unroll") for (int n = 0; n < 4; ++n)                              \
      SET[(ks) * 4 + n] = *(const short8*)(                                    \
          WbF + (((kap_ * 32 + og0 + n) * 16 + ksg_) * 64 + lane) * 8);        \
  }

// one k-slice: av from LDS, bv from regs, staging half inside, MFMA cluster
#define SLICE(bu, ks, CUR, STG)                                                \
  {                                                                            \
    short8 av[4];                                                              \
    _Pragma("unroll") for (int m = 0; m < 4; ++m) {                            \
      int row = wm * 64 + m * 16 + row_in;                                     \
      int cs = ((ks) * 4 + hi) ^ (row & 7);                                    \
      av[m] = *(const short8*)(&sA[bu][(row * 8 + cs) * 8]);                   \
    }                                                                          \
    STG;                                                                       \
    PRIO1();                                                                   \
    _Pragma("unroll") for (int m = 0; m < 4; ++m)                              \
      _Pragma("unroll") for (int n = 0; n < 4; ++n)                            \
        acc[m][n] = __builtin_amdgcn_mfma_f32_16x16x32_bf16(                   \
            av[m], CUR[(ks) * 4 + n], acc[m][n], 0, 0, 0);                     \
    PRIO0();                                                                   \
  }

#define STEP(kt, bu, bs, CUR, NXT)                                             \
  WAITVM(20); BAR(); FENCE();                                                  \
  SLICE(bu, 0, CUR, { GS_A((kt) + 2, bs, 0, 1); BVL((kt) + 2, NXT, 0); });     \
  SLICE(bu, 1, CUR, { GS_A((kt) + 2, bs, 2, 3); BVL((kt) + 2, NXT, 1); });     \
  FENCE();

  f32x4 acc[4][4] = {};
  short8 bvA[8], bvB[8], bvC[8];

  // prologue: A(0), A(1) staged; bv(0)->bvA, bv(1)->bvB (issue order matters)
  GS_A(0, 0, 0, 3);
  GS_A(1, 1, 0, 3);
  BVL(0, bvA, 0); BVL(0, bvA, 1);
  BVL(1, bvB, 0); BVL(1, bvB, 1);
  FENCE();

  for (int g = 0; g < 7; ++g) {     // kt = 0..20
    const int kt = g * 3;
    STEP(kt + 0, 0, 2, bvA, bvC);
    STEP(kt + 1, 1, 0, bvB, bvA);
    STEP(kt + 2, 2, 1, bvC, bvB);
  }
  STEP(21, 0, 2, bvA, bvC);         // stages A(23)->buf2, bv(23)->bvC
  // kt = 22: nothing to issue; in-flight = bv(22)8 + A(23)4 + bv(23)8 = 20
  WAITVM(20); BAR(); FENCE();
  SLICE(1, 0, bvB, (void)0); SLICE(1, 1, bvB, (void)0); FENCE();
  // kt = 23: drain A(23) (+bv(22)) -> keep bv(23)
  WAITVM(8); BAR(); FENCE();
  SLICE(2, 0, bvC, (void)0); SLICE(2, 1, bvC, (void)0);
#undef GS_A
#undef BVL
#undef SLICE
#undef STEP

  // epilogue: p = p0 + wm*64 + m*16 + hi*4 + r ; o = o0 + wn*64 + n*16 + row_in
#pragma unroll
  for (int m = 0; m < 4; ++m) {
    const int p = p0 + wm * 64 + m * 16 + hi * 4;
#pragma unroll
    for (int n = 0; n < 4; ++n) {
      const int o = o0 + wn * 64 + n * 16 + row_in;
#pragma unroll
      for (int r = 0; r < 4; ++r)
        out[(size_t)((b * NCT) + p + r) * ND + o] = acc[m][n][r];
    }
  }
}

// ---------------------------------------------------------------------------
extern "C" void kernel_launch(void* const* d_in, const int* in_sizes, int n_in,
                              void* d_out, int out_size, void* d_ws, size_t ws_size,
                              hipStream_t stream) {
  const float* x = (const float*)d_in[0];
  const float* bank = (const float*)d_in[1];
  const float* tw = (const float*)d_in[2];
  float* out = (float*)d_out;

  char* ws = (char*)d_ws;
  __hip_bfloat16* Apad = (__hip_bfloat16*)ws;
  __hip_bfloat16* WbF = (__hip_bfloat16*)(ws + APAD_BYTES);
  __hip_bfloat16* bankB = (__hip_bfloat16*)(ws + APAD_BYTES + WBF_BYTES);

  prep_kernel<<<256, 256, 0, stream>>>(bank, tw, WbF, bankB);
  cwt_kernel<<<256, 512, 0, stream>>>(x, bankB, Apad);
  gemm_kernel<<<256, 512, 0, stream>>>(Apad, WbF, out);
}

// Round 18
// 57.827 us; speedup vs baseline: 1.0210x; 1.0210x over previous
//
#include <hip/hip_runtime.h>
#include <hip/hip_bf16.h>

// Problem constants
#define NB 32      // batch
#define NC 8       // channels
#define NL 512     // length
#define NS 63      // scales
#define NK 1009    // max wavelet kernel length (odd)
#define NPAD 504   // (NK-1)/2
#define ND 512     // d_model
#define NCT 512    // total channels after concat = C*(1+S)
#define NROWS 514  // Apad rows per batch (circular-padded)

typedef __attribute__((ext_vector_type(4))) float f32x4;
typedef __attribute__((ext_vector_type(8))) short short8;

// Workspace layout (bytes)
#define APAD_BYTES (NB * NROWS * NL * 2)   // 16,842,752  bf16 [B][514][512]
#define WB_BYTES   (3 * ND * NL * 2)       //  1,572,864  bf16 [3][512][512]

typedef const __attribute__((address_space(1))) unsigned int* gp1_t;
typedef __attribute__((address_space(3))) unsigned int* lp3_t;
__device__ __forceinline__ void gload_lds16(const void* g, void* l) {
  __builtin_amdgcn_global_load_lds((gp1_t)g, (lp3_t)l, 16, 0, 0);
}

__device__ __forceinline__ unsigned short bf16_bits(float v) {
  return __builtin_bit_cast(unsigned short, __float2bfloat16(v));
}

#define WAITVM(N) asm volatile("s_waitcnt vmcnt(" #N ")" ::: "memory")
#define FENCE() asm volatile("" ::: "memory")
#define BAR() __builtin_amdgcn_s_barrier()
#define PRIO1() __builtin_amdgcn_s_setprio(1)
#define PRIO0() __builtin_amdgcn_s_setprio(0)

// ---------------------------------------------------------------------------
// Kernel 1: prep — Wb[k][o][l] = bf16(tw[o][l][k]); bankB[s][k] zero-padded.
// (reverted to linear Wb layout — B lives in LDS again)
// ---------------------------------------------------------------------------
__global__ __launch_bounds__(256) void prep_kernel(
    const float* __restrict__ bank, const float* __restrict__ tw,
    __hip_bfloat16* __restrict__ Wb, __hip_bfloat16* __restrict__ bankB) {
  const int idx = blockIdx.x * 256 + threadIdx.x;   // 65536 threads

  {
    int i0 = idx * 4;
    const float4* t4 = (const float4*)(tw + (size_t)i0 * 3);
    float4 a = t4[0], bq = t4[1], c4 = t4[2];
    ushort4 w0 = make_ushort4(bf16_bits(a.x), bf16_bits(a.w), bf16_bits(bq.z), bf16_bits(c4.y));
    ushort4 w1 = make_ushort4(bf16_bits(a.y), bf16_bits(bq.x), bf16_bits(bq.w), bf16_bits(c4.z));
    ushort4 w2 = make_ushort4(bf16_bits(a.z), bf16_bits(bq.y), bf16_bits(c4.x), bf16_bits(c4.w));
    *(ushort4*)(Wb + 0 * ND * NL + i0) = w0;
    *(ushort4*)(Wb + 1 * ND * NL + i0) = w1;
    *(ushort4*)(Wb + 2 * ND * NL + i0) = w2;
  }
  {
    int s = idx >> 10, k = idx & 1023;
    float v = (s < NS && k < NK) ? bank[s * NK + k] : 0.f;
    bankB[idx] = __float2bfloat16(v);
  }
}

// ---------------------------------------------------------------------------
// Kernel 2: cwt via MFMA (unchanged from R13/R16 — measured best).
// ---------------------------------------------------------------------------
#define CPY8_STRIDE 3152   // 16*197, 197 odd -> quad spread across copies

__global__ __launch_bounds__(512) void cwt_kernel(
    const float* __restrict__ x, const __hip_bfloat16* __restrict__ bankB,
    __hip_bfloat16* __restrict__ Apad) {
  __shared__ __align__(16) char smem[8 * 16384 + 8 * CPY8_STRIDE];  // 156,288 B
  char* bankS = smem;
  char* cpy = smem + 8 * 16384;

  const int tid = threadIdx.x;
  const int bc = blockIdx.x;
  const int b = bc >> 3, c = bc & 7;
  const int w = tid >> 6, l = tid & 63;
  const int hi = l >> 4, li = l & 15;
  const int r8 = l & 7;

  const float* xrow = x + bc * NL;

  if (tid < 512) {
    __hip_bfloat16 v = __float2bfloat16(xrow[tid]);
    Apad[((size_t)(b * NROWS) + 1 + c) * NL + tid] = v;
    if (c == 0) Apad[((size_t)(b * NROWS) + 513) * NL + tid] = v;
  }

  for (int i = 0; i < 13; ++i) {
    int p = tid + i * 512;
    if (p < 6176) {
      int r_ = p / 772;
      int pe = p - r_ * 772;
      int g0 = 2 * pe;
      int i0 = g0 - 8 + r_;
      float xa = (i0 >= NPAD && i0 < NPAD + NL) ? xrow[i0 - NPAD] : 0.f;
      float xb = (i0 + 1 >= NPAD && i0 + 1 < NPAD + NL) ? xrow[i0 + 1 - NPAD] : 0.f;
      float xc = (i0 + 2 >= NPAD && i0 + 2 < NPAD + NL) ? xrow[i0 + 2 - NPAD] : 0.f;
      unsigned u = (unsigned)bf16_bits(xb - xa) | ((unsigned)bf16_bits(xc - xb) << 16);
      *(unsigned*)(cpy + r_ * CPY8_STRIDE + g0 * 2) = u;
    }
  }

#define STAGE(kt)                                                             \
  {                                                                           \
    for (int i = 0; i < 2; ++i) {                                             \
      int ck = tid + i * 512;                                                 \
      int s_ = ck >> 4, rb = ck & 15;                                         \
      int srcc = rb ^ (s_ & 7);                                               \
      gload_lds16(bankB + s_ * 1024 + (kt) * 128 + srcc * 8,                  \
                  bankS + (kt) * 16384 + ck * 16);                            \
    }                                                                         \
  }

#define AVMM(kt, ksl, m)                                                       \
  {                                                                            \
    int srow = (m) * 16 + li;                                                  \
    int chunk = ((ksl) * 4 + hi) ^ (srow & 7);                                 \
    short8 av = *(const short8*)(bankS + (kt) * 16384 + srow * 256 + chunk * 16); \
    _Pragma("unroll") for (int n = 0; n < 4; ++n)                              \
      acc[m][n] = __builtin_amdgcn_mfma_f32_16x16x32_bf16(av, bv[n],           \
                                                          acc[m][n], 0, 0, 0); \
  }

#define CCOMP(kt, M0, M1, M2, M3)                                              \
  {                                                                            \
    _Pragma("unroll") for (int ksl = 0; ksl < 4; ++ksl) {                      \
      short8 bv[4];                                                            \
      _Pragma("unroll") for (int n = 0; n < 4; ++n) {                          \
        int ebyte = 16 + 2 * (tbase + n * 16 + 8 * (li >> 3) +                 \
                              (kt) * 128 + ksl * 32 + 8 * hi);                 \
        bv[n] = *(const short8*)(cpy + r8 * CPY8_STRIDE + ebyte);              \
      }                                                                        \
      if (M0) AVMM(kt, ksl, 0);                                                \
      if (M1) AVMM(kt, ksl, 1);                                                \
      if (M2) AVMM(kt, ksl, 2);                                                \
      if (M3) AVMM(kt, ksl, 3);                                                \
    }                                                                          \
  }

  STAGE(0); STAGE(1); STAGE(2); STAGE(3);
  STAGE(4); STAGE(5); STAGE(6); STAGE(7);

  f32x4 acc[4][4] = {};
  const int tbase = w * 64;

  asm volatile("s_waitcnt vmcnt(14) lgkmcnt(0)" ::: "memory");
  BAR(); FENCE(); CCOMP(0, 0, 0, 1, 1);
  WAITVM(12); BAR(); FENCE(); CCOMP(1, 0, 1, 1, 1);
  WAITVM(10); BAR(); FENCE(); CCOMP(2, 1, 1, 1, 1);
  WAITVM(8);  BAR(); FENCE(); CCOMP(3, 1, 1, 1, 1);
  WAITVM(6);  BAR(); FENCE(); CCOMP(4, 1, 1, 1, 1);
  WAITVM(4);  BAR(); FENCE(); CCOMP(5, 0, 1, 1, 1);
  WAITVM(2);  BAR(); FENCE(); CCOMP(6, 0, 0, 1, 1);
  WAITVM(0);  BAR(); FENCE(); CCOMP(7, 0, 0, 0, 1);

#pragma unroll
  for (int m = 0; m < 4; ++m) {
#pragma unroll
    for (int rg = 0; rg < 4; ++rg) {
      int s = m * 16 + hi * 4 + rg;
      if (s >= NS) continue;
      int ch = 8 + c * NS + s;
      size_t rowbase = ((size_t)(b * NROWS) + 1 + ch) * NL;
#pragma unroll
      for (int n = 0; n < 4; ++n) {
        int t = tbase + n * 16 + li;
        float d = fabsf(acc[m][n][rg]);
        __hip_bfloat16 hv = __float2bfloat16(d);
        bool lastgrp = (w == 7 && n == 3);
        bool skip = lastgrp && (li == 15);
        bool dup = lastgrp && (li == 14);
        if (!skip) Apad[rowbase + t] = hv;
        if (dup) Apad[rowbase + 511] = hv;
        if (ch == NCT - 1) {
          size_t wrapbase = (size_t)(b * NROWS) * NL;
          if (!skip) Apad[wrapbase + t] = hv;
          if (dup) Apad[wrapbase + 511] = hv;
        }
      }
    }
  }
#undef STAGE
#undef AVMM
#undef CCOMP
}

// ---------------------------------------------------------------------------
// Kernel 3: gemm — EXACT R16 pipeline (measured best) + coalesced epilogue.
// BM=256, BN=128, BK=64, 8 waves (4Mx2N), 3-buf rotation, WAITVM(6)+BAR per
// K-tile, staging halves interleaved between the two k-slice MFMA clusters.
// NEW: epilogue does an in-register 4x4 transpose (xor-butterfly, DPP
// quad-perm) so each thread writes 16 float4 (64B segments) instead of 64
// scalar dwords (16B segments).
// ---------------------------------------------------------------------------
__global__ __launch_bounds__(512) void gemm_kernel(
    const __hip_bfloat16* __restrict__ Ap, const __hip_bfloat16* __restrict__ Wb,
    float* __restrict__ out) {
  __shared__ __hip_bfloat16 sA[3][256 * 64];   // 96 KB
  __shared__ __hip_bfloat16 sB[3][128 * 64];   // 48 KB

  const int tid = threadIdx.x;                 // 0..511
  const int gid = blockIdx.x;                  // 0..255
  const int idx = gid >> 3;                    // 0..31
  const int mblk = (gid & 7) * 8 + (idx & 7);  // 0..63 (XCD-local A-slab)
  const int nblk = idx >> 3;                   // 0..3
  const int b = mblk >> 1;
  const int p0 = (mblk & 1) * 256;
  const int o0 = nblk * 128;

  const int w = tid >> 6, lane = tid & 63;
  const int wm = w >> 1, wn = w & 1;           // 4M x 2N
  const int row_in = lane & 15, hi = lane >> 4;

#define GSTAGE_H0(kt, bu)                                                      \
  {                                                                            \
    const int kap_ = (kt) >> 3;                                                \
    const int l0_ = ((kt) & 7) << 6;                                           \
    _Pragma("unroll") for (int i = 0; i < 2; ++i) {                            \
      int ck = tid + i * 512;                                                  \
      int row = ck >> 3, cg = (ck & 7) ^ (row & 7);                            \
      gload_lds16(Ap + ((b * NROWS + p0 + kap_ + row) * NL + l0_ + cg * 8),    \
                  &sA[bu][ck * 8]);                                            \
    }                                                                          \
    {                                                                          \
      int ck = tid;                                                            \
      int row = ck >> 3, cg = (ck & 7) ^ (row & 7);                            \
      gload_lds16(Wb + ((kap_ * ND + o0 + row) * NL + l0_ + cg * 8),           \
                  &sB[bu][ck * 8]);                                            \
    }                                                                          \
  }

#define GSTAGE_H1(kt, bu)                                                      \
  {                                                                            \
    const int kap_ = (kt) >> 3;                                                \
    const int l0_ = ((kt) & 7) << 6;                                           \
    _Pragma("unroll") for (int i = 2; i < 4; ++i) {                            \
      int ck = tid + i * 512;                                                  \
      int row = ck >> 3, cg = (ck & 7) ^ (row & 7);                            \
      gload_lds16(Ap + ((b * NROWS + p0 + kap_ + row) * NL + l0_ + cg * 8),    \
                  &sA[bu][ck * 8]);                                            \
    }                                                                          \
    {                                                                          \
      int ck = tid + 512;                                                      \
      int row = ck >> 3, cg = (ck & 7) ^ (row & 7);                            \
      gload_lds16(Wb + ((kap_ * ND + o0 + row) * NL + l0_ + cg * 8),           \
                  &sB[bu][ck * 8]);                                            \
    }                                                                          \
  }

#define SLICE(bu, ks, STG)                                                     \
  {                                                                            \
    short8 av[4], bv[4];                                                       \
    _Pragma("unroll") for (int m = 0; m < 4; ++m) {                            \
      int row = wm * 64 + m * 16 + row_in;                                     \
      int cs = ((ks) * 4 + hi) ^ (row & 7);                                    \
      av[m] = *(const short8*)(&sA[bu][(row * 8 + cs) * 8]);                   \
    }                                                                          \
    _Pragma("unroll") for (int n = 0; n < 4; ++n) {                            \
      int row = wn * 64 + n * 16 + row_in;                                     \
      int cs = ((ks) * 4 + hi) ^ (row & 7);                                    \
      bv[n] = *(const short8*)(&sB[bu][(row * 8 + cs) * 8]);                   \
    }                                                                          \
    STG;                                                                       \
    PRIO1();                                                                   \
    _Pragma("unroll") for (int m = 0; m < 4; ++m)                              \
      _Pragma("unroll") for (int n = 0; n < 4; ++n)                            \
        acc[m][n] = __builtin_amdgcn_mfma_f32_16x16x32_bf16(av[m], bv[n],      \
                                                            acc[m][n], 0, 0, 0); \
    PRIO0();                                                                   \
  }

#define STEP(kt, bu, bs)                                                       \
  WAITVM(6); BAR(); FENCE();                                                   \
  SLICE(bu, 0, GSTAGE_H0((kt) + 2, bs));                                       \
  SLICE(bu, 1, GSTAGE_H1((kt) + 2, bs));                                       \
  FENCE();

  f32x4 acc[4][4] = {};

  GSTAGE_H0(0, 0); GSTAGE_H1(0, 0);
  GSTAGE_H0(1, 1); GSTAGE_H1(1, 1);

  for (int g = 0; g < 7; ++g) {     // kt = 0..20
    const int kt = g * 3;
    STEP(kt + 0, 0, 2);
    STEP(kt + 1, 1, 0);
    STEP(kt + 2, 2, 1);
  }
  // kt = 21 (stages tile 23), 22, 23
  STEP(21, 0, 2);
  WAITVM(6); BAR(); FENCE(); SLICE(1, 0, (void)0); SLICE(1, 1, (void)0); FENCE();
  WAITVM(0); BAR(); FENCE(); SLICE(2, 0, (void)0); SLICE(2, 1, (void)0);
#undef GSTAGE_H0
#undef GSTAGE_H1
#undef SLICE
#undef STEP

  // epilogue: per (m,n) 4x4 xor-butterfly transpose across quad lanes, then
  // one float4 store per (m,n): lane 4q+j holds out[pbase+j][obase+0..3].
  const int j4 = lane & 3;
  const int oq = ((lane >> 2) & 3) * 4;
#pragma unroll
  for (int m = 0; m < 4; ++m) {
    const int p = p0 + wm * 64 + m * 16 + hi * 4 + j4;
#pragma unroll
    for (int n = 0; n < 4; ++n) {
      float v0 = acc[m][n][0], v1 = acc[m][n][1];
      float v2 = acc[m][n][2], v3 = acc[m][n][3];
      {  // phase k=1: pairs (0,1) and (2,3)
        float s01 = (j4 & 1) ? v0 : v1;
        float r01 = __shfl_xor(s01, 1);
        float nv0 = (j4 & 1) ? r01 : v0;
        float nv1 = (j4 & 1) ? v1 : r01;
        float s23 = (j4 & 1) ? v2 : v3;
        float r23 = __shfl_xor(s23, 1);
        float nv2 = (j4 & 1) ? r23 : v2;
        float nv3 = (j4 & 1) ? v3 : r23;
        v0 = nv0; v1 = nv1; v2 = nv2; v3 = nv3;
      }
      {  // phase k=2: pairs (0,2) and (1,3)
        float s02 = (j4 & 2) ? v0 : v2;
        float r02 = __shfl_xor(s02, 2);
        float nv0 = (j4 & 2) ? r02 : v0;
        float nv2 = (j4 & 2) ? v2 : r02;
        float s13 = (j4 & 2) ? v1 : v3;
        float r13 = __shfl_xor(s13, 2);
        float nv1 = (j4 & 2) ? r13 : v1;
        float nv3 = (j4 & 2) ? v3 : r13;
        v0 = nv0; v1 = nv1; v2 = nv2; v3 = nv3;
      }
      const int o4 = o0 + wn * 64 + n * 16 + oq;
      float4 val = make_float4(v0, v1, v2, v3);
      *(float4*)&out[(size_t)((b * NCT) + p) * ND + o4] = val;
    }
  }
}

// ---------------------------------------------------------------------------
extern "C" void kernel_launch(void* const* d_in, const int* in_sizes, int n_in,
                              void* d_out, int out_size, void* d_ws, size_t ws_size,
                              hipStream_t stream) {
  const float* x = (const float*)d_in[0];
  const float* bank = (const float*)d_in[1];
  const float* tw = (const float*)d_in[2];
  float* out = (float*)d_out;

  char* ws = (char*)d_ws;
  __hip_bfloat16* Apad = (__hip_bfloat16*)ws;
  __hip_bfloat16* Wb = (__hip_bfloat16*)(ws + APAD_BYTES);
  __hip_bfloat16* bankB = (__hip_bfloat16*)(ws + APAD_BYTES + WB_BYTES);

  prep_kernel<<<256, 256, 0, stream>>>(bank, tw, Wb, bankB);
  cwt_kernel<<<256, 512, 0, stream>>>(x, bankB, Apad);
  gemm_kernel<<<256, 512, 0, stream>>>(Apad, Wb, out);
}

// Round 19
// 56.586 us; speedup vs baseline: 1.0434x; 1.0219x over previous
//
#include <hip/hip_runtime.h>
#include <hip/hip_bf16.h>

// Problem constants
#define NB 32      // batch
#define NC 8       // channels
#define NL 512     // length
#define NS 63      // scales
#define NK 1009    // max wavelet kernel length (odd)
#define NPAD 504   // (NK-1)/2
#define ND 512     // d_model
#define NCT 512    // total channels after concat = C*(1+S)
#define NROWS 514  // Apad rows per batch (circular-padded)

typedef __attribute__((ext_vector_type(4))) float f32x4;
typedef __attribute__((ext_vector_type(8))) short short8;

// Workspace layout (bytes)
#define APAD_BYTES (NB * NROWS * NL * 2)   // 16,842,752  bf16 [B][514][512]
#define WB_BYTES   (3 * ND * NL * 2)       //  1,572,864  bf16 [3][512][512]

typedef const __attribute__((address_space(1))) unsigned int* gp1_t;
typedef __attribute__((address_space(3))) unsigned int* lp3_t;
__device__ __forceinline__ void gload_lds16(const void* g, void* l) {
  __builtin_amdgcn_global_load_lds((gp1_t)g, (lp3_t)l, 16, 0, 0);
}

__device__ __forceinline__ unsigned short bf16_bits(float v) {
  return __builtin_bit_cast(unsigned short, __float2bfloat16(v));
}

#define WAITVM(N) asm volatile("s_waitcnt vmcnt(" #N ")" ::: "memory")
#define FENCE() asm volatile("" ::: "memory")
#define BAR() __builtin_amdgcn_s_barrier()
#define PRIO1() __builtin_amdgcn_s_setprio(1)
#define PRIO0() __builtin_amdgcn_s_setprio(0)

// ---------------------------------------------------------------------------
// Kernel 1: prep — Wb[k][o][l] = bf16(tw[o][l][k]); bankB[s][k] zero-padded.
// ---------------------------------------------------------------------------
__global__ __launch_bounds__(256) void prep_kernel(
    const float* __restrict__ bank, const float* __restrict__ tw,
    __hip_bfloat16* __restrict__ Wb, __hip_bfloat16* __restrict__ bankB) {
  const int idx = blockIdx.x * 256 + threadIdx.x;   // 65536 threads

  {
    int i0 = idx * 4;
    const float4* t4 = (const float4*)(tw + (size_t)i0 * 3);
    float4 a = t4[0], bq = t4[1], c4 = t4[2];
    ushort4 w0 = make_ushort4(bf16_bits(a.x), bf16_bits(a.w), bf16_bits(bq.z), bf16_bits(c4.y));
    ushort4 w1 = make_ushort4(bf16_bits(a.y), bf16_bits(bq.x), bf16_bits(bq.w), bf16_bits(c4.z));
    ushort4 w2 = make_ushort4(bf16_bits(a.z), bf16_bits(bq.y), bf16_bits(c4.x), bf16_bits(c4.w));
    *(ushort4*)(Wb + 0 * ND * NL + i0) = w0;
    *(ushort4*)(Wb + 1 * ND * NL + i0) = w1;
    *(ushort4*)(Wb + 2 * ND * NL + i0) = w2;
  }
  {
    int s = idx >> 10, k = idx & 1023;
    float v = (s < NS && k < NK) ? bank[s * NK + k] : 0.f;
    bankB[idx] = __float2bfloat16(v);
  }
}

// ---------------------------------------------------------------------------
// Kernel 2: cwt via MFMA.  d[t][s] = | sum_k bank[s][k] * dx[t+k] |.
// R13 structure + Toeplitz bv DEDUP: per K-tile the 16 bv fragments
// (4 ksl x 4 n) have offsets n*16 + ksl*32 -> only 10 unique; load uniq[10]
// once, bv[ksl][n] = uniq[n + 2*ksl]. LDS reads/wave 220 -> 172 (-22%).
// ---------------------------------------------------------------------------
#define CPY8_STRIDE 3152   // 16*197, 197 odd -> quad spread across copies

__global__ __launch_bounds__(512) void cwt_kernel(
    const float* __restrict__ x, const __hip_bfloat16* __restrict__ bankB,
    __hip_bfloat16* __restrict__ Apad) {
  __shared__ __align__(16) char smem[8 * 16384 + 8 * CPY8_STRIDE];  // 156,288 B
  char* bankS = smem;
  char* cpy = smem + 8 * 16384;

  const int tid = threadIdx.x;
  const int bc = blockIdx.x;
  const int b = bc >> 3, c = bc & 7;
  const int w = tid >> 6, l = tid & 63;
  const int hi = l >> 4, li = l & 15;
  const int r8 = l & 7;

  const float* xrow = x + bc * NL;

  if (tid < 512) {
    __hip_bfloat16 v = __float2bfloat16(xrow[tid]);
    Apad[((size_t)(b * NROWS) + 1 + c) * NL + tid] = v;
    if (c == 0) Apad[((size_t)(b * NROWS) + 513) * NL + tid] = v;
  }

  for (int i = 0; i < 13; ++i) {
    int p = tid + i * 512;
    if (p < 6176) {
      int r_ = p / 772;
      int pe = p - r_ * 772;
      int g0 = 2 * pe;
      int i0 = g0 - 8 + r_;
      float xa = (i0 >= NPAD && i0 < NPAD + NL) ? xrow[i0 - NPAD] : 0.f;
      float xb = (i0 + 1 >= NPAD && i0 + 1 < NPAD + NL) ? xrow[i0 + 1 - NPAD] : 0.f;
      float xc = (i0 + 2 >= NPAD && i0 + 2 < NPAD + NL) ? xrow[i0 + 2 - NPAD] : 0.f;
      unsigned u = (unsigned)bf16_bits(xb - xa) | ((unsigned)bf16_bits(xc - xb) << 16);
      *(unsigned*)(cpy + r_ * CPY8_STRIDE + g0 * 2) = u;
    }
  }

#define STAGE(kt)                                                             \
  {                                                                           \
    for (int i = 0; i < 2; ++i) {                                             \
      int ck = tid + i * 512;                                                 \
      int s_ = ck >> 4, rb = ck & 15;                                         \
      int srcc = rb ^ (s_ & 7);                                               \
      gload_lds16(bankB + s_ * 1024 + (kt) * 128 + srcc * 8,                  \
                  bankS + (kt) * 16384 + ck * 16);                            \
    }                                                                         \
  }

#define AVMM(kt, ksl, m)                                                       \
  {                                                                            \
    int srow = (m) * 16 + li;                                                  \
    int chunk = ((ksl) * 4 + hi) ^ (srow & 7);                                 \
    short8 av = *(const short8*)(bankS + (kt) * 16384 + srow * 256 + chunk * 16); \
    _Pragma("unroll") for (int n = 0; n < 4; ++n)                              \
      acc[m][n] = __builtin_amdgcn_mfma_f32_16x16x32_bf16(av, bv[n],           \
                                                          acc[m][n], 0, 0, 0); \
  }

#define CCOMP(kt, M0, M1, M2, M3)                                              \
  {                                                                            \
    short8 uq[10];                                                             \
    _Pragma("unroll") for (int i = 0; i < 10; ++i) {                           \
      int ebyte = 16 + 2 * (tbase + i * 16 + 8 * (li >> 3) +                   \
                            (kt) * 128 + 8 * hi);                              \
      uq[i] = *(const short8*)(cpy + r8 * CPY8_STRIDE + ebyte);                \
    }                                                                          \
    _Pragma("unroll") for (int ksl = 0; ksl < 4; ++ksl) {                      \
      short8 bv[4];                                                            \
      bv[0] = uq[2 * ksl + 0]; bv[1] = uq[2 * ksl + 1];                        \
      bv[2] = uq[2 * ksl + 2]; bv[3] = uq[2 * ksl + 3];                        \
      if (M0) AVMM(kt, ksl, 0);                                                \
      if (M1) AVMM(kt, ksl, 1);                                                \
      if (M2) AVMM(kt, ksl, 2);                                                \
      if (M3) AVMM(kt, ksl, 3);                                                \
    }                                                                          \
  }

  STAGE(0); STAGE(1); STAGE(2); STAGE(3);
  STAGE(4); STAGE(5); STAGE(6); STAGE(7);

  f32x4 acc[4][4] = {};
  const int tbase = w * 64;

  asm volatile("s_waitcnt vmcnt(14) lgkmcnt(0)" ::: "memory");
  BAR(); FENCE(); CCOMP(0, 0, 0, 1, 1);
  WAITVM(12); BAR(); FENCE(); CCOMP(1, 0, 1, 1, 1);
  WAITVM(10); BAR(); FENCE(); CCOMP(2, 1, 1, 1, 1);
  WAITVM(8);  BAR(); FENCE(); CCOMP(3, 1, 1, 1, 1);
  WAITVM(6);  BAR(); FENCE(); CCOMP(4, 1, 1, 1, 1);
  WAITVM(4);  BAR(); FENCE(); CCOMP(5, 0, 1, 1, 1);
  WAITVM(2);  BAR(); FENCE(); CCOMP(6, 0, 0, 1, 1);
  WAITVM(0);  BAR(); FENCE(); CCOMP(7, 0, 0, 0, 1);

#pragma unroll
  for (int m = 0; m < 4; ++m) {
#pragma unroll
    for (int rg = 0; rg < 4; ++rg) {
      int s = m * 16 + hi * 4 + rg;
      if (s >= NS) continue;
      int ch = 8 + c * NS + s;
      size_t rowbase = ((size_t)(b * NROWS) + 1 + ch) * NL;
#pragma unroll
      for (int n = 0; n < 4; ++n) {
        int t = tbase + n * 16 + li;
        float d = fabsf(acc[m][n][rg]);
        __hip_bfloat16 hv = __float2bfloat16(d);
        bool lastgrp = (w == 7 && n == 3);
        bool skip = lastgrp && (li == 15);
        bool dup = lastgrp && (li == 14);
        if (!skip) Apad[rowbase + t] = hv;
        if (dup) Apad[rowbase + 511] = hv;
        if (ch == NCT - 1) {
          size_t wrapbase = (size_t)(b * NROWS) * NL;
          if (!skip) Apad[wrapbase + t] = hv;
          if (dup) Apad[wrapbase + 511] = hv;
        }
      }
    }
  }
#undef STAGE
#undef AVMM
#undef CCOMP
}

// ---------------------------------------------------------------------------
// Kernel 3: gemm — EXACT R16 configuration (measured best, 56.8 us total):
// BM=256, BN=128, BK=64, 8 waves (4Mx2N), 3-buf rotation, WAITVM(6)+BAR per
// K-tile, staging halves interleaved between the two k-slice MFMA clusters,
// scalar-store epilogue (R18's transpose epilogue was neutral/negative).
// ---------------------------------------------------------------------------
__global__ __launch_bounds__(512) void gemm_kernel(
    const __hip_bfloat16* __restrict__ Ap, const __hip_bfloat16* __restrict__ Wb,
    float* __restrict__ out) {
  __shared__ __hip_bfloat16 sA[3][256 * 64];   // 96 KB
  __shared__ __hip_bfloat16 sB[3][128 * 64];   // 48 KB

  const int tid = threadIdx.x;                 // 0..511
  const int gid = blockIdx.x;                  // 0..255
  const int idx = gid >> 3;                    // 0..31
  const int mblk = (gid & 7) * 8 + (idx & 7);  // 0..63 (XCD-local A-slab)
  const int nblk = idx >> 3;                   // 0..3
  const int b = mblk >> 1;
  const int p0 = (mblk & 1) * 256;
  const int o0 = nblk * 128;

  const int w = tid >> 6, lane = tid & 63;
  const int wm = w >> 1, wn = w & 1;           // 4M x 2N
  const int row_in = lane & 15, hi = lane >> 4;

#define GSTAGE_H0(kt, bu)                                                      \
  {                                                                            \
    const int kap_ = (kt) >> 3;                                                \
    const int l0_ = ((kt) & 7) << 6;                                           \
    _Pragma("unroll") for (int i = 0; i < 2; ++i) {                            \
      int ck = tid + i * 512;                                                  \
      int row = ck >> 3, cg = (ck & 7) ^ (row & 7);                            \
      gload_lds16(Ap + ((b * NROWS + p0 + kap_ + row) * NL + l0_ + cg * 8),    \
                  &sA[bu][ck * 8]);                                            \
    }                                                                          \
    {                                                                          \
      int ck = tid;                                                            \
      int row = ck >> 3, cg = (ck & 7) ^ (row & 7);                            \
      gload_lds16(Wb + ((kap_ * ND + o0 + row) * NL + l0_ + cg * 8),           \
                  &sB[bu][ck * 8]);                                            \
    }                                                                          \
  }

#define GSTAGE_H1(kt, bu)                                                      \
  {                                                                            \
    const int kap_ = (kt) >> 3;                                                \
    const int l0_ = ((kt) & 7) << 6;                                           \
    _Pragma("unroll") for (int i = 2; i < 4; ++i) {                            \
      int ck = tid + i * 512;                                                  \
      int row = ck >> 3, cg = (ck & 7) ^ (row & 7);                            \
      gload_lds16(Ap + ((b * NROWS + p0 + kap_ + row) * NL + l0_ + cg * 8),    \
                  &sA[bu][ck * 8]);                                            \
    }                                                                          \
    {                                                                          \
      int ck = tid + 512;                                                      \
      int row = ck >> 3, cg = (ck & 7) ^ (row & 7);                            \
      gload_lds16(Wb + ((kap_ * ND + o0 + row) * NL + l0_ + cg * 8),           \
                  &sB[bu][ck * 8]);                                            \
    }                                                                          \
  }

#define SLICE(bu, ks, STG)                                                     \
  {                                                                            \
    short8 av[4], bv[4];                                                       \
    _Pragma("unroll") for (int m = 0; m < 4; ++m) {                            \
      int row = wm * 64 + m * 16 + row_in;                                     \
      int cs = ((ks) * 4 + hi) ^ (row & 7);                                    \
      av[m] = *(const short8*)(&sA[bu][(row * 8 + cs) * 8]);                   \
    }                                                                          \
    _Pragma("unroll") for (int n = 0; n < 4; ++n) {                            \
      int row = wn * 64 + n * 16 + row_in;                                     \
      int cs = ((ks) * 4 + hi) ^ (row & 7);                                    \
      bv[n] = *(const short8*)(&sB[bu][(row * 8 + cs) * 8]);                   \
    }                                                                          \
    STG;                                                                       \
    PRIO1();                                                                   \
    _Pragma("unroll") for (int m = 0; m < 4; ++m)                              \
      _Pragma("unroll") for (int n = 0; n < 4; ++n)                            \
        acc[m][n] = __builtin_amdgcn_mfma_f32_16x16x32_bf16(av[m], bv[n],      \
                                                            acc[m][n], 0, 0, 0); \
    PRIO0();                                                                   \
  }

#define STEP(kt, bu, bs)                                                       \
  WAITVM(6); BAR(); FENCE();                                                   \
  SLICE(bu, 0, GSTAGE_H0((kt) + 2, bs));                                       \
  SLICE(bu, 1, GSTAGE_H1((kt) + 2, bs));                                       \
  FENCE();

  f32x4 acc[4][4] = {};

  GSTAGE_H0(0, 0); GSTAGE_H1(0, 0);
  GSTAGE_H0(1, 1); GSTAGE_H1(1, 1);

  for (int g = 0; g < 7; ++g) {     // kt = 0..20
    const int kt = g * 3;
    STEP(kt + 0, 0, 2);
    STEP(kt + 1, 1, 0);
    STEP(kt + 2, 2, 1);
  }
  // kt = 21 (stages tile 23), 22, 23
  STEP(21, 0, 2);
  WAITVM(6); BAR(); FENCE(); SLICE(1, 0, (void)0); SLICE(1, 1, (void)0); FENCE();
  WAITVM(0); BAR(); FENCE(); SLICE(2, 0, (void)0); SLICE(2, 1, (void)0);
#undef GSTAGE_H0
#undef GSTAGE_H1
#undef SLICE
#undef STEP

  // epilogue: p = p0 + wm*64 + m*16 + hi*4 + r ; o = o0 + wn*64 + n*16 + row_in
#pragma unroll
  for (int m = 0; m < 4; ++m) {
    const int p = p0 + wm * 64 + m * 16 + hi * 4;
#pragma unroll
    for (int n = 0; n < 4; ++n) {
      const int o = o0 + wn * 64 + n * 16 + row_in;
#pragma unroll
      for (int r = 0; r < 4; ++r)
        out[(size_t)((b * NCT) + p + r) * ND + o] = acc[m][n][r];
    }
  }
}

// ---------------------------------------------------------------------------
extern "C" void kernel_launch(void* const* d_in, const int* in_sizes, int n_in,
                              void* d_out, int out_size, void* d_ws, size_t ws_size,
                              hipStream_t stream) {
  const float* x = (const float*)d_in[0];
  const float* bank = (const float*)d_in[1];
  const float* tw = (const float*)d_in[2];
  float* out = (float*)d_out;

  char* ws = (char*)d_ws;
  __hip_bfloat16* Apad = (__hip_bfloat16*)ws;
  __hip_bfloat16* Wb = (__hip_bfloat16*)(ws + APAD_BYTES);
  __hip_bfloat16* bankB = (__hip_bfloat16*)(ws + APAD_BYTES + WB_BYTES);

  prep_kernel<<<256, 256, 0, stream>>>(bank, tw, Wb, bankB);
  cwt_kernel<<<256, 512, 0, stream>>>(x, bankB, Apad);
  gemm_kernel<<<256, 512, 0, stream>>>(Apad, Wb, out);
}

// Round 20
// 56.231 us; speedup vs baseline: 1.0500x; 1.0063x over previous
//
#include <hip/hip_runtime.h>
#include <hip/hip_bf16.h>

// Problem constants
#define NB 32      // batch
#define NC 8       // channels
#define NL 512     // length
#define NS 63      // scales
#define NK 1009    // max wavelet kernel length (odd)
#define NPAD 504   // (NK-1)/2
#define ND 512     // d_model
#define NCT 512    // total channels after concat = C*(1+S)
#define NROWS 514  // Apad rows per batch (circular-padded)

typedef __attribute__((ext_vector_type(4))) float f32x4;
typedef __attribute__((ext_vector_type(8))) short short8;

// Workspace layout (bytes)
#define APAD_BYTES (NB * NROWS * NL * 2)   // 16,842,752  bf16 [B][514][512]
#define WB_BYTES   (3 * ND * NL * 2)       //  1,572,864  bf16 [3][512][512]

typedef const __attribute__((address_space(1))) unsigned int* gp1_t;
typedef __attribute__((address_space(3))) unsigned int* lp3_t;
__device__ __forceinline__ void gload_lds16(const void* g, void* l) {
  __builtin_amdgcn_global_load_lds((gp1_t)g, (lp3_t)l, 16, 0, 0);
}

__device__ __forceinline__ unsigned short bf16_bits(float v) {
  return __builtin_bit_cast(unsigned short, __float2bfloat16(v));
}

#define WAITVM(N) asm volatile("s_waitcnt vmcnt(" #N ")" ::: "memory")
#define FENCE() asm volatile("" ::: "memory")
#define BAR() __builtin_amdgcn_s_barrier()
#define PRIO1() __builtin_amdgcn_s_setprio(1)
#define PRIO0() __builtin_amdgcn_s_setprio(0)

// ---------------------------------------------------------------------------
// Kernel 1: prep — Wb[k][o][l] = bf16(tw[o][l][k]); bankB[s][k] zero-padded.
// ---------------------------------------------------------------------------
__global__ __launch_bounds__(256) void prep_kernel(
    const float* __restrict__ bank, const float* __restrict__ tw,
    __hip_bfloat16* __restrict__ Wb, __hip_bfloat16* __restrict__ bankB) {
  const int idx = blockIdx.x * 256 + threadIdx.x;   // 65536 threads

  {
    int i0 = idx * 4;
    const float4* t4 = (const float4*)(tw + (size_t)i0 * 3);
    float4 a = t4[0], bq = t4[1], c4 = t4[2];
    ushort4 w0 = make_ushort4(bf16_bits(a.x), bf16_bits(a.w), bf16_bits(bq.z), bf16_bits(c4.y));
    ushort4 w1 = make_ushort4(bf16_bits(a.y), bf16_bits(bq.x), bf16_bits(bq.w), bf16_bits(c4.z));
    ushort4 w2 = make_ushort4(bf16_bits(a.z), bf16_bits(bq.y), bf16_bits(c4.x), bf16_bits(c4.w));
    *(ushort4*)(Wb + 0 * ND * NL + i0) = w0;
    *(ushort4*)(Wb + 1 * ND * NL + i0) = w1;
    *(ushort4*)(Wb + 2 * ND * NL + i0) = w2;
  }
  {
    int s = idx >> 10, k = idx & 1023;
    float v = (s < NS && k < NK) ? bank[s * NK + k] : 0.f;
    bankB[idx] = __float2bfloat16(v);
  }
}

// ---------------------------------------------------------------------------
// Kernel 2: cwt via MFMA.  d[t][s] = | sum_k bank[s][k] * dx[t+k] |.
// NEW: 3-buffer rotating bank staging (48KB) + dx copies (24.6KB) = 74.4KB
// LDS -> 2 blocks/CU; __launch_bounds__(512,4) caps VGPR at 128 (4 wv/SIMD).
// Hazard skeleton mirrors the proven R16 gemm: per tile WAITVM(2); BAR;
// STAGE(kt+2 -> (kt+2)%3) post-barrier; CCOMP(kt from kt%3). Explicit
// WAITVM(0) after dx fill pins the vmcnt baseline; first wait adds lgkm(0).
// bv fragments: 10 unique per tile held in 6 rotating regs (q0..q5).
// Zero-tile masks kept (m0 kt2-4, m1 kt1-5, m2 kt0-6, m3 all).
// ---------------------------------------------------------------------------
#define CPY8_STRIDE 3152   // 16*197, 197 odd -> quad spread across copies

__global__ __launch_bounds__(512, 4) void cwt_kernel(
    const float* __restrict__ x, const __hip_bfloat16* __restrict__ bankB,
    __hip_bfloat16* __restrict__ Apad) {
  __shared__ __align__(16) char smem[3 * 16384 + 8 * CPY8_STRIDE];  // 74,368 B
  char* bankS = smem;
  char* cpy = smem + 3 * 16384;

  const int tid = threadIdx.x;
  const int bc = blockIdx.x;
  const int b = bc >> 3, c = bc & 7;
  const int w = tid >> 6, l = tid & 63;
  const int hi = l >> 4, li = l & 15;
  const int r8 = l & 7;

  const float* xrow = x + bc * NL;

  if (tid < 512) {
    __hip_bfloat16 v = __float2bfloat16(xrow[tid]);
    Apad[((size_t)(b * NROWS) + 1 + c) * NL + tid] = v;
    if (c == 0) Apad[((size_t)(b * NROWS) + 513) * NL + tid] = v;
  }

  for (int i = 0; i < 13; ++i) {
    int p = tid + i * 512;
    if (p < 6176) {
      int r_ = p / 772;
      int pe = p - r_ * 772;
      int g0 = 2 * pe;
      int i0 = g0 - 8 + r_;
      float xa = (i0 >= NPAD && i0 < NPAD + NL) ? xrow[i0 - NPAD] : 0.f;
      float xb = (i0 + 1 >= NPAD && i0 + 1 < NPAD + NL) ? xrow[i0 + 1 - NPAD] : 0.f;
      float xc = (i0 + 2 >= NPAD && i0 + 2 < NPAD + NL) ? xrow[i0 + 2 - NPAD] : 0.f;
      unsigned u = (unsigned)bf16_bits(xb - xa) | ((unsigned)bf16_bits(xc - xb) << 16);
      *(unsigned*)(cpy + r_ * CPY8_STRIDE + g0 * 2) = u;
    }
  }

  WAITVM(0);   // pin vmcnt baseline: Apad stores + dx loads fully drained

#define STAGE(kt, bu)                                                         \
  {                                                                           \
    for (int i = 0; i < 2; ++i) {                                             \
      int ck = tid + i * 512;                                                 \
      int s_ = ck >> 4, rb = ck & 15;                                         \
      int srcc = rb ^ (s_ & 7);                                               \
      gload_lds16(bankB + s_ * 1024 + (kt) * 128 + srcc * 8,                  \
                  bankS + (bu) * 16384 + ck * 16);                            \
    }                                                                         \
  }

// unique bv fragment i (offset i*16 elems) of tile kt
#define LDU(kt, i)                                                            \
  (*(const short8*)(cpy + r8 * CPY8_STRIDE + 16 +                             \
                    2 * (tbase + (i) * 16 + 8 * (li >> 3) + (kt) * 128 + 8 * hi)))

// av(m) x {B0..B3} -> acc[m][0..3]
#define AVMM4(kt, bu, ksl, m, B0, B1, B2, B3)                                  \
  {                                                                            \
    int srow = (m) * 16 + li;                                                  \
    int chunk = ((ksl) * 4 + hi) ^ (srow & 7);                                 \
    short8 av = *(const short8*)(bankS + (bu) * 16384 + srow * 256 + chunk * 16); \
    acc[m][0] = __builtin_amdgcn_mfma_f32_16x16x32_bf16(av, B0, acc[m][0], 0, 0, 0); \
    acc[m][1] = __builtin_amdgcn_mfma_f32_16x16x32_bf16(av, B1, acc[m][1], 0, 0, 0); \
    acc[m][2] = __builtin_amdgcn_mfma_f32_16x16x32_bf16(av, B2, acc[m][2], 0, 0, 0); \
    acc[m][3] = __builtin_amdgcn_mfma_f32_16x16x32_bf16(av, B3, acc[m][3], 0, 0, 0); \
  }

// one K-tile, 6-register uq rotation: ksl0 uses u0..u3, ksl1 u2..u5,
// then reload u6..u9 into q0..q3; ksl2 uses u4,u5,u6,u7; ksl3 u6..u9.
#define CCOMP(kt, bu, M0, M1, M2, M3)                                          \
  {                                                                            \
    short8 q0 = LDU(kt, 0), q1 = LDU(kt, 1), q2 = LDU(kt, 2);                  \
    short8 q3 = LDU(kt, 3), q4 = LDU(kt, 4), q5 = LDU(kt, 5);                  \
    if (M0) AVMM4(kt, bu, 0, 0, q0, q1, q2, q3);                               \
    if (M1) AVMM4(kt, bu, 0, 1, q0, q1, q2, q3);                               \
    if (M2) AVMM4(kt, bu, 0, 2, q0, q1, q2, q3);                               \
    if (M3) AVMM4(kt, bu, 0, 3, q0, q1, q2, q3);                               \
    if (M0) AVMM4(kt, bu, 1, 0, q2, q3, q4, q5);                               \
    if (M1) AVMM4(kt, bu, 1, 1, q2, q3, q4, q5);                               \
    if (M2) AVMM4(kt, bu, 1, 2, q2, q3, q4, q5);                               \
    if (M3) AVMM4(kt, bu, 1, 3, q2, q3, q4, q5);                               \
    q0 = LDU(kt, 6); q1 = LDU(kt, 7); q2 = LDU(kt, 8); q3 = LDU(kt, 9);        \
    if (M0) AVMM4(kt, bu, 2, 0, q4, q5, q0, q1);                               \
    if (M1) AVMM4(kt, bu, 2, 1, q4, q5, q0, q1);                               \
    if (M2) AVMM4(kt, bu, 2, 2, q4, q5, q0, q1);                               \
    if (M3) AVMM4(kt, bu, 2, 3, q4, q5, q0, q1);                               \
    if (M0) AVMM4(kt, bu, 3, 0, q0, q1, q2, q3);                               \
    if (M1) AVMM4(kt, bu, 3, 1, q0, q1, q2, q3);                               \
    if (M2) AVMM4(kt, bu, 3, 2, q0, q1, q2, q3);                               \
    if (M3) AVMM4(kt, bu, 3, 3, q0, q1, q2, q3);                               \
  }

  f32x4 acc[4][4] = {};
  const int tbase = w * 64;

  STAGE(0, 0); STAGE(1, 1);     // 4 loads in flight

  // per tile: drain kt (keep kt+1), barrier, stage kt+2, compute kt
  asm volatile("s_waitcnt vmcnt(2) lgkmcnt(0)" ::: "memory");
  BAR(); FENCE(); STAGE(2, 2); CCOMP(0, 0, 0, 0, 1, 1); FENCE();
  WAITVM(2); BAR(); FENCE(); STAGE(3, 0); CCOMP(1, 1, 0, 1, 1, 1); FENCE();
  WAITVM(2); BAR(); FENCE(); STAGE(4, 1); CCOMP(2, 2, 1, 1, 1, 1); FENCE();
  WAITVM(2); BAR(); FENCE(); STAGE(5, 2); CCOMP(3, 0, 1, 1, 1, 1); FENCE();
  WAITVM(2); BAR(); FENCE(); STAGE(6, 0); CCOMP(4, 1, 1, 1, 1, 1); FENCE();
  WAITVM(2); BAR(); FENCE(); STAGE(7, 1); CCOMP(5, 2, 0, 1, 1, 1); FENCE();
  WAITVM(2); BAR(); FENCE(); CCOMP(6, 0, 0, 0, 1, 1); FENCE();
  WAITVM(0); BAR(); FENCE(); CCOMP(7, 1, 0, 0, 0, 1);

#pragma unroll
  for (int m = 0; m < 4; ++m) {
#pragma unroll
    for (int rg = 0; rg < 4; ++rg) {
      int s = m * 16 + hi * 4 + rg;
      if (s >= NS) continue;
      int ch = 8 + c * NS + s;
      size_t rowbase = ((size_t)(b * NROWS) + 1 + ch) * NL;
#pragma unroll
      for (int n = 0; n < 4; ++n) {
        int t = tbase + n * 16 + li;
        float d = fabsf(acc[m][n][rg]);
        __hip_bfloat16 hv = __float2bfloat16(d);
        bool lastgrp = (w == 7 && n == 3);
        bool skip = lastgrp && (li == 15);
        bool dup = lastgrp && (li == 14);
        if (!skip) Apad[rowbase + t] = hv;
        if (dup) Apad[rowbase + 511] = hv;
        if (ch == NCT - 1) {
          size_t wrapbase = (size_t)(b * NROWS) * NL;
          if (!skip) Apad[wrapbase + t] = hv;
          if (dup) Apad[wrapbase + 511] = hv;
        }
      }
    }
  }
#undef STAGE
#undef LDU
#undef AVMM4
#undef CCOMP
}

// ---------------------------------------------------------------------------
// Kernel 3: gemm — EXACT R16 configuration (measured best):
// BM=256, BN=128, BK=64, 8 waves (4Mx2N), 3-buf rotation, WAITVM(6)+BAR per
// K-tile, staging halves interleaved between the two k-slice MFMA clusters,
// scalar-store epilogue.
// ---------------------------------------------------------------------------
__global__ __launch_bounds__(512) void gemm_kernel(
    const __hip_bfloat16* __restrict__ Ap, const __hip_bfloat16* __restrict__ Wb,
    float* __restrict__ out) {
  __shared__ __hip_bfloat16 sA[3][256 * 64];   // 96 KB
  __shared__ __hip_bfloat16 sB[3][128 * 64];   // 48 KB

  const int tid = threadIdx.x;                 // 0..511
  const int gid = blockIdx.x;                  // 0..255
  const int idx = gid >> 3;                    // 0..31
  const int mblk = (gid & 7) * 8 + (idx & 7);  // 0..63 (XCD-local A-slab)
  const int nblk = idx >> 3;                   // 0..3
  const int b = mblk >> 1;
  const int p0 = (mblk & 1) * 256;
  const int o0 = nblk * 128;

  const int w = tid >> 6, lane = tid & 63;
  const int wm = w >> 1, wn = w & 1;           // 4M x 2N
  const int row_in = lane & 15, hi = lane >> 4;

#define GSTAGE_H0(kt, bu)                                                      \
  {                                                                            \
    const int kap_ = (kt) >> 3;                                                \
    const int l0_ = ((kt) & 7) << 6;                                           \
    _Pragma("unroll") for (int i = 0; i < 2; ++i) {                            \
      int ck = tid + i * 512;                                                  \
      int row = ck >> 3, cg = (ck & 7) ^ (row & 7);                            \
      gload_lds16(Ap + ((b * NROWS + p0 + kap_ + row) * NL + l0_ + cg * 8),    \
                  &sA[bu][ck * 8]);                                            \
    }                                                                          \
    {                                                                          \
      int ck = tid;                                                            \
      int row = ck >> 3, cg = (ck & 7) ^ (row & 7);                            \
      gload_lds16(Wb + ((kap_ * ND + o0 + row) * NL + l0_ + cg * 8),           \
                  &sB[bu][ck * 8]);                                            \
    }                                                                          \
  }

#define GSTAGE_H1(kt, bu)                                                      \
  {                                                                            \
    const int kap_ = (kt) >> 3;                                                \
    const int l0_ = ((kt) & 7) << 6;                                           \
    _Pragma("unroll") for (int i = 2; i < 4; ++i) {                            \
      int ck = tid + i * 512;                                                  \
      int row = ck >> 3, cg = (ck & 7) ^ (row & 7);                            \
      gload_lds16(Ap + ((b * NROWS + p0 + kap_ + row) * NL + l0_ + cg * 8),    \
                  &sA[bu][ck * 8]);                                            \
    }                                                                          \
    {                                                                          \
      int ck = tid + 512;                                                      \
      int row = ck >> 3, cg = (ck & 7) ^ (row & 7);                            \
      gload_lds16(Wb + ((kap_ * ND + o0 + row) * NL + l0_ + cg * 8),           \
                  &sB[bu][ck * 8]);                                            \
    }                                                                          \
  }

#define SLICE(bu, ks, STG)                                                     \
  {                                                                            \
    short8 av[4], bv[4];                                                       \
    _Pragma("unroll") for (int m = 0; m < 4; ++m) {                            \
      int row = wm * 64 + m * 16 + row_in;                                     \
      int cs = ((ks) * 4 + hi) ^ (row & 7);                                    \
      av[m] = *(const short8*)(&sA[bu][(row * 8 + cs) * 8]);                   \
    }                                                                          \
    _Pragma("unroll") for (int n = 0; n < 4; ++n) {                            \
      int row = wn * 64 + n * 16 + row_in;                                     \
      int cs = ((ks) * 4 + hi) ^ (row & 7);                                    \
      bv[n] = *(const short8*)(&sB[bu][(row * 8 + cs) * 8]);                   \
    }                                                                          \
    STG;                                                                       \
    PRIO1();                                                                   \
    _Pragma("unroll") for (int m = 0; m < 4; ++m)                              \
      _Pragma("unroll") for (int n = 0; n < 4; ++n)                            \
        acc[m][n] = __builtin_amdgcn_mfma_f32_16x16x32_bf16(av[m], bv[n],      \
                                                            acc[m][n], 0, 0, 0); \
    PRIO0();                                                                   \
  }

#define STEP(kt, bu, bs)                                                       \
  WAITVM(6); BAR(); FENCE();                                                   \
  SLICE(bu, 0, GSTAGE_H0((kt) + 2, bs));                                       \
  SLICE(bu, 1, GSTAGE_H1((kt) + 2, bs));                                       \
  FENCE();

  f32x4 acc[4][4] = {};

  GSTAGE_H0(0, 0); GSTAGE_H1(0, 0);
  GSTAGE_H0(1, 1); GSTAGE_H1(1, 1);

  for (int g = 0; g < 7; ++g) {     // kt = 0..20
    const int kt = g * 3;
    STEP(kt + 0, 0, 2);
    STEP(kt + 1, 1, 0);
    STEP(kt + 2, 2, 1);
  }
  // kt = 21 (stages tile 23), 22, 23
  STEP(21, 0, 2);
  WAITVM(6); BAR(); FENCE(); SLICE(1, 0, (void)0); SLICE(1, 1, (void)0); FENCE();
  WAITVM(0); BAR(); FENCE(); SLICE(2, 0, (void)0); SLICE(2, 1, (void)0);
#undef GSTAGE_H0
#undef GSTAGE_H1
#undef SLICE
#undef STEP

  // epilogue: p = p0 + wm*64 + m*16 + hi*4 + r ; o = o0 + wn*64 + n*16 + row_in
#pragma unroll
  for (int m = 0; m < 4; ++m) {
    const int p = p0 + wm * 64 + m * 16 + hi * 4;
#pragma unroll
    for (int n = 0; n < 4; ++n) {
      const int o = o0 + wn * 64 + n * 16 + row_in;
#pragma unroll
      for (int r = 0; r < 4; ++r)
        out[(size_t)((b * NCT) + p + r) * ND + o] = acc[m][n][r];
    }
  }
}

// ---------------------------------------------------------------------------
extern "C" void kernel_launch(void* const* d_in, const int* in_sizes, int n_in,
                              void* d_out, int out_size, void* d_ws, size_t ws_size,
                              hipStream_t stream) {
  const float* x = (const float*)d_in[0];
  const float* bank = (const float*)d_in[1];
  const float* tw = (const float*)d_in[2];
  float* out = (float*)d_out;

  char* ws = (char*)d_ws;
  __hip_bfloat16* Apad = (__hip_bfloat16*)ws;
  __hip_bfloat16* Wb = (__hip_bfloat16*)(ws + APAD_BYTES);
  __hip_bfloat16* bankB = (__hip_bfloat16*)(ws + APAD_BYTES + WB_BYTES);

  prep_kernel<<<256, 256, 0, stream>>>(bank, tw, Wb, bankB);
  cwt_kernel<<<256, 512, 0, stream>>>(x, bankB, Apad);
  gemm_kernel<<<256, 512, 0, stream>>>(Apad, Wb, out);
}